// Round 4
// baseline (222.783 us; speedup 1.0000x reference)
//
#include <hip/hip_runtime.h>

// EndEffectorLoss: rot6d -> R, FK over fixed 24-joint tree, end-effector MSE.
// R4: LDS-staged, fully-coalesced loading. 256 threads = 256 (frame,pose)
// units (128 frames x {A,B}); joints processed in 4 stages of 6, one reused
// LDS buffer (~64 KB -> 2 blocks/CU co-resident so staging of one block
// overlaps compute of the other). All global reads are lane-contiguous b32;
// per-lane FK reads come from LDS (padded rows, gcd(pad,32)=1 -> <=2 lanes/bank).
// amdgpu_waves_per_eu(2) => 256-VGPR budget => no scratch spill (R2/R3 bug).

struct V3 { float x, y, z; };
struct M3 { float m[3][3]; };   // row r = basis vector b_r (row-stacked)

__device__ __forceinline__ V3 matvec(const M3& A, const V3& v) {
    return { A.m[0][0]*v.x + A.m[0][1]*v.y + A.m[0][2]*v.z,
             A.m[1][0]*v.x + A.m[1][1]*v.y + A.m[1][2]*v.z,
             A.m[2][0]*v.x + A.m[2][1]*v.y + A.m[2][2]*v.z };
}

__device__ __forceinline__ M3 matmul(const M3& A, const M3& B) {
    M3 C;
#pragma unroll
    for (int i = 0; i < 3; i++)
#pragma unroll
        for (int j = 0; j < 3; j++)
            C.m[i][j] = A.m[i][0]*B.m[0][j] + A.m[i][1]*B.m[1][j] + A.m[i][2]*B.m[2][j];
    return C;
}

#define PPAD 37   // 36 pose words/stage + 1 (gcd(37,32)=1 -> conflict-free)
#define OPAD 19   // 18 off words/stage + 1 (gcd(19,32)=1)

struct FK { M3 o; V3 p; };

// Gram-Schmidt from 6 LDS floats (matches jnp reference, f32).
__device__ __forceinline__ M3 rot6d_lds(const float* __restrict__ sp, int base) {
    float v0 = sp[base+0], v1 = sp[base+1], v2 = sp[base+2];
    float v3 = sp[base+3], v4 = sp[base+4], v5 = sp[base+5];
    float n1 = v0*v0 + v1*v1 + v2*v2;
    float r1 = 1.0f / sqrtf(n1);
    V3 b1 = { v0*r1, v1*r1, v2*r1 };
    float d = b1.x*v3 + b1.y*v4 + b1.z*v5;
    V3 u = { v3 - d*b1.x, v4 - d*b1.y, v5 - d*b1.z };
    float n2 = u.x*u.x + u.y*u.y + u.z*u.z;
    float r2 = 1.0f / sqrtf(n2);
    V3 b2 = { u.x*r2, u.y*r2, u.z*r2 };
    V3 b3 = { b1.y*b2.z - b1.z*b2.y, b1.z*b2.x - b1.x*b2.z, b1.x*b2.y - b1.y*b2.x };
    M3 R;
    R.m[0][0]=b1.x; R.m[0][1]=b1.y; R.m[0][2]=b1.z;
    R.m[1][0]=b2.x; R.m[1][1]=b2.y; R.m[1][2]=b2.z;
    R.m[2][0]=b3.x; R.m[2][1]=b3.y; R.m[2][2]=b3.z;
    return R;
}

__device__ __forceinline__ FK fk_step_l(const float* __restrict__ sp,
                                        const float* __restrict__ so,
                                        int pbase, int obase, const FK& par) {
    V3 off = { so[obase], so[obase+1], so[obase+2] };
    V3 t = matvec(par.o, off);
    FK s;
    s.p = { par.p.x + t.x, par.p.y + t.y, par.p.z + t.z };
    s.o = matmul(par.o, rot6d_lds(sp, pbase));
    return s;
}

__device__ __forceinline__ V3 fk_end_l(const float* __restrict__ so,
                                       int obase, const FK& par) {
    V3 off = { so[obase], so[obase+1], so[obase+2] };
    V3 t = matvec(par.o, off);
    return { par.p.x + t.x, par.p.y + t.y, par.p.z + t.z };
}

__global__ __launch_bounds__(256)
__attribute__((amdgpu_waves_per_eu(2)))   // 256-VGPR budget: forbid spill
void ee_loss_kernel(const float* __restrict__ poseA, const float* __restrict__ poseB,
                    const float* __restrict__ offA,  const float* __restrict__ offB,
                    const float* __restrict__ tA,    const float* __restrict__ tB,
                    float* __restrict__ out, float inv_count) {
    __shared__ float s_pose[256 * PPAD];   // 37.9 KB
    __shared__ float s_off [256 * OPAD];   // 19.5 KB
    __shared__ float s_eeB[128][15];       // 7.7 KB (stride 15, gcd(15,32)=1)
    __shared__ float s_inv[6];
    __shared__ float s_d[15];
    __shared__ float s_part[2];

    const int tid = threadIdx.x;
    const int fl  = tid & 127;
    const bool isB = tid >= 128;
    const int f0w_p = blockIdx.x * 128 * 144;   // base float index into pose arrays
    const int f0w_o = blockIdx.x * 128 * 72;    // base float index into off arrays
    const float* pA = poseA + f0w_p;
    const float* pB = poseB + f0w_p;
    const float* oA = offA  + f0w_o;
    const float* oB = offB  + f0w_o;

    // ---- t_pose-derived constants (tiny, before first barrier) ----
    if (tid < 6) {
        const float* tp = (tid < 3) ? tA : tB;
        int ax = (tid < 3) ? tid : tid - 3;
        float mn = tp[ax], mx = mn;
#pragma unroll
        for (int j = 1; j < 24; j++) {
            float v = tp[j*3 + ax];
            mn = fminf(mn, v); mx = fmaxf(mx, v);
        }
        s_inv[tid] = 1.0f / (mx - mn);
    }
    if (tid < 15) {
        const int EE[5] = {10, 11, 15, 22, 23};
        int e = tid / 3, ax = tid - 3*e;
        int j = EE[e];
        float mnA = tA[ax], mxA = mnA, mnB = tB[ax], mxB = mnB;
#pragma unroll
        for (int k = 1; k < 24; k++) {
            float a = tA[k*3 + ax], b = tB[k*3 + ax];
            mnA = fminf(mnA, a); mxA = fmaxf(mxA, a);
            mnB = fminf(mnB, b); mxB = fmaxf(mxB, b);
        }
        s_d[tid] = tB[j*3 + ax]/(mxB - mnB) - tA[j*3 + ax]/(mxA - mnA);
    }

    // ---- coalesced staging of one 6-joint chunk (stage st) ----
    auto stage = [&](int st) {
        const int ps = st * 36, os = st * 18;
        // pose A: 128 frames x 36 words; lane-contiguous reads, dst = i + i/36
#pragma unroll
        for (int k = 0; k < 18; k++) {
            int i = tid + k * 256;
            int flr = i / 36, w = i - flr * 36;
            s_pose[flr * PPAD + w] = pA[flr * 144 + ps + w];
        }
#pragma unroll
        for (int k = 0; k < 18; k++) {
            int i = tid + k * 256;
            int flr = i / 36, w = i - flr * 36;
            s_pose[(128 + flr) * PPAD + w] = pB[flr * 144 + ps + w];
        }
#pragma unroll
        for (int k = 0; k < 9; k++) {
            int i = tid + k * 256;
            int flr = i / 18, w = i - flr * 18;
            s_off[flr * OPAD + w] = oA[flr * 72 + os + w];
        }
#pragma unroll
        for (int k = 0; k < 9; k++) {
            int i = tid + k * 256;
            int flr = i / 18, w = i - flr * 18;
            s_off[(128 + flr) * OPAD + w] = oB[flr * 72 + os + w];
        }
    };

    const float* sp = s_pose + tid * PPAD;
    const float* so = s_off  + tid * OPAD;

    // ---- stage 0: joints 0..5 ----
    stage(0);
    __syncthreads();
    FK s0; s0.o = rot6d_lds(sp, 0); s0.p = { so[0], so[1], so[2] };
    FK s1 = fk_step_l(sp, so,  6,  3, s0);
    FK s2 = fk_step_l(sp, so, 12,  6, s0);
    FK s3 = fk_step_l(sp, so, 18,  9, s0);
    FK s4 = fk_step_l(sp, so, 24, 12, s1);
    FK s5 = fk_step_l(sp, so, 30, 15, s2);
    __syncthreads();                      // reads done; buffer may be overwritten

    // ---- stage 1: joints 6..11 (10,11 are end sites: offsets only) ----
    stage(1);
    __syncthreads();
    FK s6 = fk_step_l(sp, so,  0,  0, s3);
    FK s7 = fk_step_l(sp, so,  6,  3, s4);
    FK s8 = fk_step_l(sp, so, 12,  6, s5);
    FK s9 = fk_step_l(sp, so, 18,  9, s6);
    V3 e10 = fk_end_l(so, 12, s7);
    V3 e11 = fk_end_l(so, 15, s8);
    __syncthreads();

    // ---- stage 2: joints 12..17 (15 end site) ----
    stage(2);
    __syncthreads();
    FK s12 = fk_step_l(sp, so,  0,  0, s9);
    FK s13 = fk_step_l(sp, so,  6,  3, s9);
    FK s14 = fk_step_l(sp, so, 12,  6, s9);
    V3 e15 = fk_end_l(so, 9, s12);
    FK s16 = fk_step_l(sp, so, 24, 12, s13);
    FK s17 = fk_step_l(sp, so, 30, 15, s14);
    __syncthreads();

    // ---- stage 3: joints 18..23 (22,23 end sites) ----
    stage(3);
    __syncthreads();
    FK s18 = fk_step_l(sp, so,  0,  0, s16);
    FK s19 = fk_step_l(sp, so,  6,  3, s17);
    FK s20 = fk_step_l(sp, so, 12,  6, s18);
    FK s21 = fk_step_l(sp, so, 18,  9, s19);
    V3 e22 = fk_end_l(so, 12, s20);
    V3 e23 = fk_end_l(so, 15, s21);
    __syncthreads();                      // before eeB reuse of LDS phase

    // ---- exchange B results, diff on A threads, reduce ----
    if (isB) {
        s_eeB[fl][ 0] = e10.x; s_eeB[fl][ 1] = e10.y; s_eeB[fl][ 2] = e10.z;
        s_eeB[fl][ 3] = e11.x; s_eeB[fl][ 4] = e11.y; s_eeB[fl][ 5] = e11.z;
        s_eeB[fl][ 6] = e15.x; s_eeB[fl][ 7] = e15.y; s_eeB[fl][ 8] = e15.z;
        s_eeB[fl][ 9] = e22.x; s_eeB[fl][10] = e22.y; s_eeB[fl][11] = e22.z;
        s_eeB[fl][12] = e23.x; s_eeB[fl][13] = e23.y; s_eeB[fl][14] = e23.z;
    }
    __syncthreads();

    float local = 0.0f;
    if (!isB) {
        float eeA[15] = { e10.x, e10.y, e10.z, e11.x, e11.y, e11.z,
                          e15.x, e15.y, e15.z, e22.x, e22.y, e22.z,
                          e23.x, e23.y, e23.z };
#pragma unroll
        for (int i = 0; i < 15; i++) {
            int ax = i % 3;   // constant after unroll
            float t = eeA[i]*s_inv[ax] - s_eeB[fl][i]*s_inv[3 + ax] + s_d[i];
            local += t * t;
        }
        local *= inv_count;
#pragma unroll
        for (int off = 32; off > 0; off >>= 1)
            local += __shfl_down(local, off, 64);
        if ((tid & 63) == 0) s_part[tid >> 6] = local;
    }
    __syncthreads();
    if (tid == 0) atomicAdd(out, s_part[0] + s_part[1]);
}

extern "C" void kernel_launch(void* const* d_in, const int* in_sizes, int n_in,
                              void* d_out, int out_size, void* d_ws, size_t ws_size,
                              hipStream_t stream) {
    const float* poseA = (const float*)d_in[0];
    const float* poseB = (const float*)d_in[1];
    const float* offA  = (const float*)d_in[2];
    const float* offB  = (const float*)d_in[3];
    const float* tA    = (const float*)d_in[4];
    const float* tB    = (const float*)d_in[5];
    float* out = (float*)d_out;

    const int F = in_sizes[0] / 144;          // 65536
    const int blocks = F / 128;               // 128 frames/block -> 512 blocks
    const float inv_count = 1.0f / ((float)F * 15.0f);

    hipMemsetAsync(out, 0, sizeof(float), stream);
    ee_loss_kernel<<<blocks, 256, 0, stream>>>(poseA, poseB, offA, offB, tA, tB,
                                               out, inv_count);
}

// Round 5
// 207.401 us; speedup vs baseline: 1.0742x; 1.0742x over previous
//
#include <hip/hip_runtime.h>

// EndEffectorLoss: rot6d -> R, FK over fixed 24-joint tree, end-effector MSE.
// R5: 5-chain decomposition, one chain x one pose per THREAD, one chain per
// BLOCK (wave-uniform, scalar branch). 256-thread blocks = {A,B} x 128 frames;
// grid = 5 chains x 512 frame-groups = 2560 blocks (10240 waves -> 32/CU).
// No launch-bounds VGPR squeeze (R3 bug) and no multi-state live set across
// barriers (R4 bug): live state = 1 FK state + pipelined loads, ~50 VGPR.
// Block order c*512+g with 512 % 8 == 0 -> all 5 chains of a frame-group land
// on the same XCD (round-robin heuristic) -> shared joints 0/3/6/9 hit L2.
//
// Chains: 0: 0-1-4-7->ee10   1: 0-2-5-8->ee11   2: 0-3-6-9-12->ee15
//         3: 0-3-6-9-13-16-18-20->ee22          4: 0-3-6-9-14-17-19-21->ee23

struct V3 { float x, y, z; };
struct M3 { float m[3][3]; };   // row r = basis vector b_r (row-stacked)

__device__ __forceinline__ V3 matvec(const M3& A, const V3& v) {
    return { A.m[0][0]*v.x + A.m[0][1]*v.y + A.m[0][2]*v.z,
             A.m[1][0]*v.x + A.m[1][1]*v.y + A.m[1][2]*v.z,
             A.m[2][0]*v.x + A.m[2][1]*v.y + A.m[2][2]*v.z };
}

__device__ __forceinline__ M3 matmul(const M3& A, const M3& B) {
    M3 C;
#pragma unroll
    for (int i = 0; i < 3; i++)
#pragma unroll
        for (int j = 0; j < 3; j++)
            C.m[i][j] = A.m[i][0]*B.m[0][j] + A.m[i][1]*B.m[1][j] + A.m[i][2]*B.m[2][j];
    return C;
}

// Pose joint J: 6 floats at frame + 6J; frame base 16B-aligned (576B/frame).
template<int J>
__device__ __forceinline__ M3 rot6d_j(const float* __restrict__ frame) {
    const float* p = frame + 6 * J;
    float v0, v1, v2, v3, v4, v5;
    if constexpr ((J & 1) == 0) {
        float4 a = *(const float4*)p;
        float2 b = *(const float2*)(p + 4);
        v0 = a.x; v1 = a.y; v2 = a.z; v3 = a.w; v4 = b.x; v5 = b.y;
    } else {
        float2 a = *(const float2*)p;
        float4 b = *(const float4*)(p + 2);
        v0 = a.x; v1 = a.y; v2 = b.x; v3 = b.y; v4 = b.z; v5 = b.w;
    }
    float n1 = v0*v0 + v1*v1 + v2*v2;
    float r1 = 1.0f / sqrtf(n1);
    V3 b1 = { v0*r1, v1*r1, v2*r1 };
    float d = b1.x*v3 + b1.y*v4 + b1.z*v5;
    V3 u = { v3 - d*b1.x, v4 - d*b1.y, v5 - d*b1.z };
    float n2 = u.x*u.x + u.y*u.y + u.z*u.z;
    float r2 = 1.0f / sqrtf(n2);
    V3 b2 = { u.x*r2, u.y*r2, u.z*r2 };
    V3 b3 = { b1.y*b2.z - b1.z*b2.y, b1.z*b2.x - b1.x*b2.z, b1.x*b2.y - b1.y*b2.x };
    M3 R;
    R.m[0][0]=b1.x; R.m[0][1]=b1.y; R.m[0][2]=b1.z;
    R.m[1][0]=b2.x; R.m[1][1]=b2.y; R.m[1][2]=b2.z;
    R.m[2][0]=b3.x; R.m[2][1]=b3.y; R.m[2][2]=b3.z;
    return R;
}

// Offset joint J: 3 floats at obase + 3J; obase 16B-aligned (288B/frame).
template<int J>
__device__ __forceinline__ V3 load_off_j(const float* __restrict__ obase) {
    const float* p = obase + 3 * J;
    if constexpr ((J & 1) == 0) {
        float2 a = *(const float2*)p;
        float  b = p[2];
        return { a.x, a.y, b };
    } else {
        float  a = p[0];
        float2 b = *(const float2*)(p + 1);
        return { a, b.x, b.y };
    }
}

struct FK { M3 o; V3 p; };

template<int J>
__device__ __forceinline__ FK fk_step(const float* __restrict__ frame,
                                      const float* __restrict__ obase,
                                      const FK& par) {
    V3 off = load_off_j<J>(obase);
    V3 t = matvec(par.o, off);
    FK s;
    s.p = { par.p.x + t.x, par.p.y + t.y, par.p.z + t.z };
    s.o = matmul(par.o, rot6d_j<J>(frame));
    return s;
}

template<int J>
__device__ __forceinline__ V3 fk_end(const float* __restrict__ obase, const FK& par) {
    V3 off = load_off_j<J>(obase);
    V3 t = matvec(par.o, off);
    return { par.p.x + t.x, par.p.y + t.y, par.p.z + t.z };
}

__global__ __launch_bounds__(256)
void ee_loss_kernel(const float* __restrict__ poseA, const float* __restrict__ poseB,
                    const float* __restrict__ offA,  const float* __restrict__ offB,
                    const float* __restrict__ tA,    const float* __restrict__ tB,
                    float* __restrict__ out, float inv_count) {
    const int tid   = threadIdx.x;
    const int fl    = tid & 127;         // frame-local 0..127
    const bool isB  = tid >= 128;
    const int chain = blockIdx.x >> 9;   // 0..4 (block-uniform -> scalar branch)
    const int fg    = blockIdx.x & 511;
    const long long f = (long long)fg * 128 + fl;

    const float* frame = (isB ? poseB : poseA) + f * 144;
    const float* obase = (isB ? offB  : offA ) + f * 72;

    __shared__ float s_eeB[128][3];      // stride 3: gcd(3,32)=1, conflict-free
    __shared__ float s_cst[9];           // invA[3], invB[3], d_chain[3]
    __shared__ float s_part[2];

    // t_pose constants for THIS chain only (3 threads, tiny, L1/L2-hit).
    if (tid < 3) {
        const int ax = tid;
        float mnA = tA[ax], mxA = mnA, mnB = tB[ax], mxB = mnB;
#pragma unroll
        for (int k = 1; k < 24; k++) {
            float a = tA[k*3 + ax], b = tB[k*3 + ax];
            mnA = fminf(mnA, a); mxA = fmaxf(mxA, a);
            mnB = fminf(mnB, b); mxB = fmaxf(mxB, b);
        }
        float invA = 1.0f / (mxA - mnA);
        float invB = 1.0f / (mxB - mnB);
        const int EE[5] = {10, 11, 15, 22, 23};
        int j = EE[chain];
        s_cst[ax]     = invA;
        s_cst[3 + ax] = invB;
        s_cst[6 + ax] = tB[j*3 + ax]*invB - tA[j*3 + ax]*invA;
    }

    // One straight-line chain (block-uniform branch; single live FK state).
    V3 e;
    {
        FK s; s.o = rot6d_j<0>(frame); s.p = load_off_j<0>(obase);
        if (chain == 0) {
            s = fk_step<1>(frame, obase, s);
            s = fk_step<4>(frame, obase, s);
            s = fk_step<7>(frame, obase, s);
            e = fk_end<10>(obase, s);
        } else if (chain == 1) {
            s = fk_step<2>(frame, obase, s);
            s = fk_step<5>(frame, obase, s);
            s = fk_step<8>(frame, obase, s);
            e = fk_end<11>(obase, s);
        } else if (chain == 2) {
            s = fk_step<3>(frame, obase, s);
            s = fk_step<6>(frame, obase, s);
            s = fk_step<9>(frame, obase, s);
            s = fk_step<12>(frame, obase, s);
            e = fk_end<15>(obase, s);
        } else if (chain == 3) {
            s = fk_step<3>(frame, obase, s);
            s = fk_step<6>(frame, obase, s);
            s = fk_step<9>(frame, obase, s);
            s = fk_step<13>(frame, obase, s);
            s = fk_step<16>(frame, obase, s);
            s = fk_step<18>(frame, obase, s);
            s = fk_step<20>(frame, obase, s);
            e = fk_end<22>(obase, s);
        } else {
            s = fk_step<3>(frame, obase, s);
            s = fk_step<6>(frame, obase, s);
            s = fk_step<9>(frame, obase, s);
            s = fk_step<14>(frame, obase, s);
            s = fk_step<17>(frame, obase, s);
            s = fk_step<19>(frame, obase, s);
            s = fk_step<21>(frame, obase, s);
            e = fk_end<23>(obase, s);
        }
    }

    if (isB) {
        s_eeB[fl][0] = e.x;
        s_eeB[fl][1] = e.y;
        s_eeB[fl][2] = e.z;
    }
    __syncthreads();

    float local = 0.0f;
    if (!isB) {
        float tx = e.x*s_cst[0] - s_eeB[fl][0]*s_cst[3] + s_cst[6];
        float ty = e.y*s_cst[1] - s_eeB[fl][1]*s_cst[4] + s_cst[7];
        float tz = e.z*s_cst[2] - s_eeB[fl][2]*s_cst[5] + s_cst[8];
        local = (tx*tx + ty*ty + tz*tz) * inv_count;
#pragma unroll
        for (int off = 32; off > 0; off >>= 1)
            local += __shfl_down(local, off, 64);
        if ((tid & 63) == 0) s_part[tid >> 6] = local;
    }
    __syncthreads();
    if (tid == 0) atomicAdd(out, s_part[0] + s_part[1]);
}

extern "C" void kernel_launch(void* const* d_in, const int* in_sizes, int n_in,
                              void* d_out, int out_size, void* d_ws, size_t ws_size,
                              hipStream_t stream) {
    const float* poseA = (const float*)d_in[0];
    const float* poseB = (const float*)d_in[1];
    const float* offA  = (const float*)d_in[2];
    const float* offB  = (const float*)d_in[3];
    const float* tA    = (const float*)d_in[4];
    const float* tB    = (const float*)d_in[5];
    float* out = (float*)d_out;

    const int F = in_sizes[0] / 144;          // 65536
    const int fgroups = F / 128;              // 512
    const int blocks = 5 * fgroups;           // 2560: chain-major (c*512+g)
    const float inv_count = 1.0f / ((float)F * 15.0f);

    hipMemsetAsync(out, 0, sizeof(float), stream);
    ee_loss_kernel<<<blocks, 256, 0, stream>>>(poseA, poseB, offA, offB, tA, tB,
                                               out, inv_count);
}

// Round 6
// 167.413 us; speedup vs baseline: 1.3307x; 1.2389x over previous
//
#include <hip/hip_runtime.h>

// EndEffectorLoss: rot6d -> R, FK over fixed 24-joint tree, end-effector MSE.
// R6 = R3 structure WITHOUT the VGPR squeeze (R3's 36-VGPR strangulation was
// the sole cause of its 51 MB spill; R5 proved the chain code runs at 52 VGPR
// spill-free). 5 straight-line chains x {A,B} = 10 waves per 640-thread block,
// 64 frames/block: all readers of a frame's cache lines are CONCURRENT in one
// block (fixes R5's 3x fetch blowup), each thread runs one chain with a single
// live FK state (fixes R1/R2/R4 spills), all load addresses are compile-time
// offsets -> compiler hoists loads chain-deep (latency hiding via MLP + 30
// waves/CU occupancy).
//
// Chains: T0: 0-1-4-7->ee10   T1: 0-2-5-8->ee11   T2: 0-3-6-9-12->ee15
//         T3: 0-3-6-9-13-16-18-20->ee22   T4: 0-3-6-9-14-17-19-21->ee23

struct V3 { float x, y, z; };
struct M3 { float m[3][3]; };   // row r = basis vector b_r (row-stacked)

__device__ __forceinline__ V3 matvec(const M3& A, const V3& v) {
    return { A.m[0][0]*v.x + A.m[0][1]*v.y + A.m[0][2]*v.z,
             A.m[1][0]*v.x + A.m[1][1]*v.y + A.m[1][2]*v.z,
             A.m[2][0]*v.x + A.m[2][1]*v.y + A.m[2][2]*v.z };
}

__device__ __forceinline__ M3 matmul(const M3& A, const M3& B) {
    M3 C;
#pragma unroll
    for (int i = 0; i < 3; i++)
#pragma unroll
        for (int j = 0; j < 3; j++)
            C.m[i][j] = A.m[i][0]*B.m[0][j] + A.m[i][1]*B.m[1][j] + A.m[i][2]*B.m[2][j];
    return C;
}

// Pose joint J: 6 floats at frame + 6J; frame base 16B-aligned (576B/frame).
template<int J>
__device__ __forceinline__ M3 rot6d_j(const float* __restrict__ frame) {
    const float* p = frame + 6 * J;
    float v0, v1, v2, v3, v4, v5;
    if constexpr ((J & 1) == 0) {
        float4 a = *(const float4*)p;
        float2 b = *(const float2*)(p + 4);
        v0 = a.x; v1 = a.y; v2 = a.z; v3 = a.w; v4 = b.x; v5 = b.y;
    } else {
        float2 a = *(const float2*)p;
        float4 b = *(const float4*)(p + 2);
        v0 = a.x; v1 = a.y; v2 = b.x; v3 = b.y; v4 = b.z; v5 = b.w;
    }
    float n1 = v0*v0 + v1*v1 + v2*v2;
    float r1 = 1.0f / sqrtf(n1);
    V3 b1 = { v0*r1, v1*r1, v2*r1 };
    float d = b1.x*v3 + b1.y*v4 + b1.z*v5;
    V3 u = { v3 - d*b1.x, v4 - d*b1.y, v5 - d*b1.z };
    float n2 = u.x*u.x + u.y*u.y + u.z*u.z;
    float r2 = 1.0f / sqrtf(n2);
    V3 b2 = { u.x*r2, u.y*r2, u.z*r2 };
    V3 b3 = { b1.y*b2.z - b1.z*b2.y, b1.z*b2.x - b1.x*b2.z, b1.x*b2.y - b1.y*b2.x };
    M3 R;
    R.m[0][0]=b1.x; R.m[0][1]=b1.y; R.m[0][2]=b1.z;
    R.m[1][0]=b2.x; R.m[1][1]=b2.y; R.m[1][2]=b2.z;
    R.m[2][0]=b3.x; R.m[2][1]=b3.y; R.m[2][2]=b3.z;
    return R;
}

// Offset joint J: 3 floats at obase + 3J; obase 16B-aligned (288B/frame).
template<int J>
__device__ __forceinline__ V3 load_off_j(const float* __restrict__ obase) {
    const float* p = obase + 3 * J;
    if constexpr ((J & 1) == 0) {
        float2 a = *(const float2*)p;
        float  b = p[2];
        return { a.x, a.y, b };
    } else {
        float  a = p[0];
        float2 b = *(const float2*)(p + 1);
        return { a, b.x, b.y };
    }
}

struct FK { M3 o; V3 p; };

template<int J>
__device__ __forceinline__ FK fk_step(const float* __restrict__ frame,
                                      const float* __restrict__ obase,
                                      const FK& par) {
    V3 off = load_off_j<J>(obase);
    V3 t = matvec(par.o, off);
    FK s;
    s.p = { par.p.x + t.x, par.p.y + t.y, par.p.z + t.z };
    s.o = matmul(par.o, rot6d_j<J>(frame));
    return s;
}

template<int J>
__device__ __forceinline__ V3 fk_end(const float* __restrict__ obase, const FK& par) {
    V3 off = load_off_j<J>(obase);
    V3 t = matvec(par.o, off);
    return { par.p.x + t.x, par.p.y + t.y, par.p.z + t.z };
}

__global__ __launch_bounds__(640)   // NO min-waves arg: full VGPR budget, no spill
void ee_loss_kernel(const float* __restrict__ poseA, const float* __restrict__ poseB,
                    const float* __restrict__ offA,  const float* __restrict__ offB,
                    const float* __restrict__ tA,    const float* __restrict__ tB,
                    float* __restrict__ out, float inv_count) {
    const int tid  = threadIdx.x;
    const int wid  = tid >> 6;           // 0..9
    const int lane = tid & 63;
    const int task = wid >> 1;           // 0..4  (wave-uniform)
    const bool isB = wid & 1;
    const long long f = (long long)blockIdx.x * 64 + lane;

    const float* frame = (isB ? poseB : poseA) + f * 144;
    const float* obase = (isB ? offB  : offA ) + f * 72;

    __shared__ float s_eeB[64][15];      // stride 15: gcd(15,32)=1, conflict-free
    __shared__ float s_inv[6];           // 1/scaleA(xyz), 1/scaleB(xyz)
    __shared__ float s_d[15];            // tB[ee]/sB - tA[ee]/sA
    __shared__ float s_part[5];

    // t_pose-derived constants (tiny, L2-resident; producers in wave 0,
    // single barrier below covers consumers).
    if (tid < 6) {
        const float* tp = (tid < 3) ? tA : tB;
        int ax = (tid < 3) ? tid : tid - 3;
        float mn = tp[ax], mx = mn;
#pragma unroll
        for (int j = 1; j < 24; j++) {
            float v = tp[j*3 + ax];
            mn = fminf(mn, v); mx = fmaxf(mx, v);
        }
        s_inv[tid] = 1.0f / (mx - mn);
    }
    if (tid < 15) {
        const int EE[5] = {10, 11, 15, 22, 23};
        int e = tid / 3, ax = tid - 3*e;
        int j = EE[e];
        float mnA = tA[ax], mxA = mnA, mnB = tB[ax], mxB = mnB;
#pragma unroll
        for (int k = 1; k < 24; k++) {
            float a = tA[k*3 + ax], b = tB[k*3 + ax];
            mnA = fminf(mnA, a); mxA = fmaxf(mxA, a);
            mnB = fminf(mnB, b); mxB = fmaxf(mxB, b);
        }
        s_d[tid] = tB[j*3 + ax]/(mxB - mnB) - tA[j*3 + ax]/(mxA - mnA);
    }

    // One straight-line chain per wave (wave-uniform branch, single FK state).
    V3 e;
    {
        FK s; s.o = rot6d_j<0>(frame); s.p = load_off_j<0>(obase);
        if (task == 0) {
            s = fk_step<1>(frame, obase, s);
            s = fk_step<4>(frame, obase, s);
            s = fk_step<7>(frame, obase, s);
            e = fk_end<10>(obase, s);
        } else if (task == 1) {
            s = fk_step<2>(frame, obase, s);
            s = fk_step<5>(frame, obase, s);
            s = fk_step<8>(frame, obase, s);
            e = fk_end<11>(obase, s);
        } else if (task == 2) {
            s = fk_step<3>(frame, obase, s);
            s = fk_step<6>(frame, obase, s);
            s = fk_step<9>(frame, obase, s);
            s = fk_step<12>(frame, obase, s);
            e = fk_end<15>(obase, s);
        } else if (task == 3) {
            s = fk_step<3>(frame, obase, s);
            s = fk_step<6>(frame, obase, s);
            s = fk_step<9>(frame, obase, s);
            s = fk_step<13>(frame, obase, s);
            s = fk_step<16>(frame, obase, s);
            s = fk_step<18>(frame, obase, s);
            s = fk_step<20>(frame, obase, s);
            e = fk_end<22>(obase, s);
        } else {
            s = fk_step<3>(frame, obase, s);
            s = fk_step<6>(frame, obase, s);
            s = fk_step<9>(frame, obase, s);
            s = fk_step<14>(frame, obase, s);
            s = fk_step<17>(frame, obase, s);
            s = fk_step<19>(frame, obase, s);
            s = fk_step<21>(frame, obase, s);
            e = fk_end<23>(obase, s);
        }
    }

    const int col0 = task * 3;
    if (isB) {
        s_eeB[lane][col0 + 0] = e.x;
        s_eeB[lane][col0 + 1] = e.y;
        s_eeB[lane][col0 + 2] = e.z;
    }
    __syncthreads();

    float local = 0.0f;
    if (!isB) {
        float tx = e.x*s_inv[0] - s_eeB[lane][col0 + 0]*s_inv[3] + s_d[col0 + 0];
        float ty = e.y*s_inv[1] - s_eeB[lane][col0 + 1]*s_inv[4] + s_d[col0 + 1];
        float tz = e.z*s_inv[2] - s_eeB[lane][col0 + 2]*s_inv[5] + s_d[col0 + 2];
        local = (tx*tx + ty*ty + tz*tz) * inv_count;
#pragma unroll
        for (int off = 32; off > 0; off >>= 1)
            local += __shfl_down(local, off, 64);
        if (lane == 0) s_part[task] = local;
    }
    __syncthreads();
    if (tid == 0)
        atomicAdd(out, ((s_part[0] + s_part[1]) + (s_part[2] + s_part[3])) + s_part[4]);
}

extern "C" void kernel_launch(void* const* d_in, const int* in_sizes, int n_in,
                              void* d_out, int out_size, void* d_ws, size_t ws_size,
                              hipStream_t stream) {
    const float* poseA = (const float*)d_in[0];
    const float* poseB = (const float*)d_in[1];
    const float* offA  = (const float*)d_in[2];
    const float* offB  = (const float*)d_in[3];
    const float* tA    = (const float*)d_in[4];
    const float* tB    = (const float*)d_in[5];
    float* out = (float*)d_out;

    const int F = in_sizes[0] / 144;          // 65536
    const int blocks = F / 64;                // 64 frames/block, 10 waves/block
    const float inv_count = 1.0f / ((float)F * 15.0f);

    hipMemsetAsync(out, 0, sizeof(float), stream);
    ee_loss_kernel<<<blocks, 640, 0, stream>>>(poseA, poseB, offA, offB, tA, tB,
                                               out, inv_count);
}

// Round 7
// 147.270 us; speedup vs baseline: 1.5127x; 1.1368x over previous
//
#include <hip/hip_runtime.h>

// EndEffectorLoss: rot6d -> R, FK over fixed 24-joint tree, end-effector MSE.
// R7: WAVE-PRIVATE LDS staging. Each wave = 64 frames x one pose; frame data
// is loaded frame-transposed (lane i takes the i-th float4 of the wave's
// concatenated frame-chunks -> ~10 consecutive frames per load instruction,
// ~20 cache lines/KB instead of 64 lines/256B for per-lane access = 6x fewer
// TA/L1 transactions). FK runs from LDS (ds_read ~120cy vs ~900cy global) in
// 6 stages of 4 joints, one reused wave-private buffer -- NO __syncthreads
// inside the FK (wave lockstep + lgkmcnt), so no barrier-fragmented live
// ranges (R4's spill cause). Global loads of stage k+1 hoist over FK(k).
// One barrier total for the A/B exchange. LDS 46.7KB -> 2 blocks/CU, grid 512.

struct V3 { float x, y, z; };
struct M3 { float m[3][3]; };   // row r = basis vector b_r (row-stacked)

__device__ __forceinline__ V3 matvec(const M3& A, const V3& v) {
    return { A.m[0][0]*v.x + A.m[0][1]*v.y + A.m[0][2]*v.z,
             A.m[1][0]*v.x + A.m[1][1]*v.y + A.m[1][2]*v.z,
             A.m[2][0]*v.x + A.m[2][1]*v.y + A.m[2][2]*v.z };
}

__device__ __forceinline__ M3 matmul(const M3& A, const M3& B) {
    M3 C;
#pragma unroll
    for (int i = 0; i < 3; i++)
#pragma unroll
        for (int j = 0; j < 3; j++)
            C.m[i][j] = A.m[i][0]*B.m[0][j] + A.m[i][1]*B.m[1][j] + A.m[i][2]*B.m[2][j];
    return C;
}

#define PROW 25   // 24 pose words/stage + 1 pad (25 coprime 32 -> 2-way = free)
#define OROW 13   // 12 off words/stage + 1 pad (13 coprime 32)

struct FK { M3 o; V3 p; };

// Gram-Schmidt from 6 LDS floats (matches jnp reference, f32).
__device__ __forceinline__ M3 rot6d_lds(const float* __restrict__ rp, int base) {
    float v0 = rp[base+0], v1 = rp[base+1], v2 = rp[base+2];
    float v3 = rp[base+3], v4 = rp[base+4], v5 = rp[base+5];
    float n1 = v0*v0 + v1*v1 + v2*v2;
    float r1 = 1.0f / sqrtf(n1);
    V3 b1 = { v0*r1, v1*r1, v2*r1 };
    float d = b1.x*v3 + b1.y*v4 + b1.z*v5;
    V3 u = { v3 - d*b1.x, v4 - d*b1.y, v5 - d*b1.z };
    float n2 = u.x*u.x + u.y*u.y + u.z*u.z;
    float r2 = 1.0f / sqrtf(n2);
    V3 b2 = { u.x*r2, u.y*r2, u.z*r2 };
    V3 b3 = { b1.y*b2.z - b1.z*b2.y, b1.z*b2.x - b1.x*b2.z, b1.x*b2.y - b1.y*b2.x };
    M3 R;
    R.m[0][0]=b1.x; R.m[0][1]=b1.y; R.m[0][2]=b1.z;
    R.m[1][0]=b2.x; R.m[1][1]=b2.y; R.m[1][2]=b2.z;
    R.m[2][0]=b3.x; R.m[2][1]=b3.y; R.m[2][2]=b3.z;
    return R;
}

__device__ __forceinline__ FK fk_step_l(const float* __restrict__ rp,
                                        const float* __restrict__ ro,
                                        int pb, int ob, const FK& par) {
    V3 off = { ro[ob], ro[ob+1], ro[ob+2] };
    V3 t = matvec(par.o, off);
    FK s;
    s.p = { par.p.x + t.x, par.p.y + t.y, par.p.z + t.z };
    s.o = matmul(par.o, rot6d_lds(rp, pb));
    return s;
}

__device__ __forceinline__ V3 fk_end_l(const float* __restrict__ ro,
                                       int ob, const FK& par) {
    V3 off = { ro[ob], ro[ob+1], ro[ob+2] };
    V3 t = matvec(par.o, off);
    return { par.p.x + t.x, par.p.y + t.y, par.p.z + t.z };
}

__global__ __launch_bounds__(256)
void ee_loss_kernel(const float* __restrict__ poseA, const float* __restrict__ poseB,
                    const float* __restrict__ offA,  const float* __restrict__ offB,
                    const float* __restrict__ tA,    const float* __restrict__ tB,
                    float* __restrict__ out, float inv_count) {
    __shared__ float s_pose[4][64 * PROW];   // 25.0 KB (wave-private slices)
    __shared__ float s_off [4][64 * OROW];   // 13.0 KB
    __shared__ float s_eeB[128][15];         // 7.5 KB (stride 15, coprime 32)
    __shared__ float s_inv[6];
    __shared__ float s_d[15];
    __shared__ float s_part[2];

    const int tid  = threadIdx.x;
    const int wid  = tid >> 6;            // 0..3
    const int lane = tid & 63;
    const bool isB = wid & 1;             // waves 1,3 -> pose B
    const int fg   = wid >> 1;            // frame-group 0/1 within block
    const int fl   = fg * 64 + lane;      // frame-local 0..127
    const long long f0 = (long long)blockIdx.x * 128 + fg * 64;  // wave frame base

    const float* __restrict__ P = (isB ? poseB : poseA) + f0 * 144;
    const float* __restrict__ O = (isB ? offB  : offA ) + f0 * 72;

    float* sp = s_pose[wid];              // this wave's slices
    float* so = s_off[wid];
    const float* rp = sp + lane * PROW;   // this thread's frame rows
    const float* ro = so + lane * OROW;

    // ---- t_pose-derived constants (tiny; consumed after the one barrier) ----
    if (tid < 6) {
        const float* tp = (tid < 3) ? tA : tB;
        int ax = (tid < 3) ? tid : tid - 3;
        float mn = tp[ax], mx = mn;
#pragma unroll
        for (int j = 1; j < 24; j++) {
            float v = tp[j*3 + ax];
            mn = fminf(mn, v); mx = fmaxf(mx, v);
        }
        s_inv[tid] = 1.0f / (mx - mn);
    }
    if (tid < 15) {
        const int EE[5] = {10, 11, 15, 22, 23};
        int e = tid / 3, ax = tid - 3*e;
        int j = EE[e];
        float mnA = tA[ax], mxA = mnA, mnB = tB[ax], mxB = mnB;
#pragma unroll
        for (int k = 1; k < 24; k++) {
            float a = tA[k*3 + ax], b = tB[k*3 + ax];
            mnA = fminf(mnA, a); mxA = fmaxf(mxA, a);
            mnB = fminf(mnB, b); mxB = fmaxf(mxB, b);
        }
        s_d[tid] = tB[j*3 + ax]/(mxB - mnB) - tA[j*3 + ax]/(mxA - mnA);
    }

    // ---- wave-private coalesced staging of 4 joints (stage st) ----
    // pose: 64 frames x 24 words = 384 float4 across 64 lanes (6 each);
    // off:  64 frames x 12 words = 384 float2 across 64 lanes (6 each).
    // Global addresses 16B/8B aligned for all f,st,c. No barrier: wave-private.
    auto stageP = [&](int st) {
#pragma unroll
        for (int k = 0; k < 6; k++) {
            int idx = lane + 64 * k;
            int f = idx / 6, c = idx - 6 * f;
            float4 v = *(const float4*)(P + f*144 + st*24 + c*4);
            float* d = sp + f*PROW + c*4;
            d[0] = v.x; d[1] = v.y; d[2] = v.z; d[3] = v.w;
        }
#pragma unroll
        for (int k = 0; k < 6; k++) {
            int idx = lane + 64 * k;
            int f = idx / 6, c = idx - 6 * f;
            float2 v = *(const float2*)(O + f*72 + st*12 + c*2);
            float* d = so + f*OROW + c*2;
            d[0] = v.x; d[1] = v.y;
        }
    };

    // ---- 6 stages of 4 joints; FK(st) reads precede stage(st+1) writes ----
    stageP(0);                                          // joints 0..3
    FK s0; s0.o = rot6d_lds(rp, 0); s0.p = { ro[0], ro[1], ro[2] };
    FK s1 = fk_step_l(rp, ro,  6, 3, s0);
    FK s2 = fk_step_l(rp, ro, 12, 6, s0);
    FK s3 = fk_step_l(rp, ro, 18, 9, s0);

    stageP(1);                                          // joints 4..7
    FK s4 = fk_step_l(rp, ro,  0, 0, s1);
    FK s5 = fk_step_l(rp, ro,  6, 3, s2);
    FK s6 = fk_step_l(rp, ro, 12, 6, s3);
    FK s7 = fk_step_l(rp, ro, 18, 9, s4);

    stageP(2);                                          // joints 8..11 (10,11 end)
    FK s8 = fk_step_l(rp, ro,  0, 0, s5);
    FK s9 = fk_step_l(rp, ro,  6, 3, s6);
    V3 e10 = fk_end_l(ro, 6, s7);
    V3 e11 = fk_end_l(ro, 9, s8);

    stageP(3);                                          // joints 12..15 (15 end)
    FK s12 = fk_step_l(rp, ro,  0, 0, s9);
    FK s13 = fk_step_l(rp, ro,  6, 3, s9);
    FK s14 = fk_step_l(rp, ro, 12, 6, s9);
    V3 e15 = fk_end_l(ro, 9, s12);

    stageP(4);                                          // joints 16..19
    FK s16 = fk_step_l(rp, ro,  0, 0, s13);
    FK s17 = fk_step_l(rp, ro,  6, 3, s14);
    FK s18 = fk_step_l(rp, ro, 12, 6, s16);
    FK s19 = fk_step_l(rp, ro, 18, 9, s17);

    stageP(5);                                          // joints 20..23 (22,23 end)
    FK s20 = fk_step_l(rp, ro,  0, 0, s18);
    FK s21 = fk_step_l(rp, ro,  6, 3, s19);
    V3 e22 = fk_end_l(ro, 6, s20);
    V3 e23 = fk_end_l(ro, 9, s21);

    // ---- exchange B results (one barrier), diff on A threads, reduce ----
    if (isB) {
        s_eeB[fl][ 0] = e10.x; s_eeB[fl][ 1] = e10.y; s_eeB[fl][ 2] = e10.z;
        s_eeB[fl][ 3] = e11.x; s_eeB[fl][ 4] = e11.y; s_eeB[fl][ 5] = e11.z;
        s_eeB[fl][ 6] = e15.x; s_eeB[fl][ 7] = e15.y; s_eeB[fl][ 8] = e15.z;
        s_eeB[fl][ 9] = e22.x; s_eeB[fl][10] = e22.y; s_eeB[fl][11] = e22.z;
        s_eeB[fl][12] = e23.x; s_eeB[fl][13] = e23.y; s_eeB[fl][14] = e23.z;
    }
    __syncthreads();

    float local = 0.0f;
    if (!isB) {
        const float iax = s_inv[0], iay = s_inv[1], iaz = s_inv[2];
        const float ibx = s_inv[3], iby = s_inv[4], ibz = s_inv[5];
        const float* eb = s_eeB[fl];
        float t0  = e10.x*iax - eb[ 0]*ibx + s_d[ 0];
        float t1  = e10.y*iay - eb[ 1]*iby + s_d[ 1];
        float t2  = e10.z*iaz - eb[ 2]*ibz + s_d[ 2];
        float t3  = e11.x*iax - eb[ 3]*ibx + s_d[ 3];
        float t4  = e11.y*iay - eb[ 4]*iby + s_d[ 4];
        float t5  = e11.z*iaz - eb[ 5]*ibz + s_d[ 5];
        float t6  = e15.x*iax - eb[ 6]*ibx + s_d[ 6];
        float t7  = e15.y*iay - eb[ 7]*iby + s_d[ 7];
        float t8  = e15.z*iaz - eb[ 8]*ibz + s_d[ 8];
        float t9  = e22.x*iax - eb[ 9]*ibx + s_d[ 9];
        float t10 = e22.y*iay - eb[10]*iby + s_d[10];
        float t11 = e22.z*iaz - eb[11]*ibz + s_d[11];
        float t12 = e23.x*iax - eb[12]*ibx + s_d[12];
        float t13 = e23.y*iay - eb[13]*iby + s_d[13];
        float t14 = e23.z*iaz - eb[14]*ibz + s_d[14];
        local = ((t0*t0 + t1*t1) + (t2*t2 + t3*t3) + (t4*t4 + t5*t5) +
                 (t6*t6 + t7*t7) + (t8*t8 + t9*t9) + (t10*t10 + t11*t11) +
                 (t12*t12 + t13*t13) + t14*t14) * inv_count;
#pragma unroll
        for (int off = 32; off > 0; off >>= 1)
            local += __shfl_down(local, off, 64);
        if (lane == 0) s_part[fg] = local;
    }
    __syncthreads();
    if (tid == 0) atomicAdd(out, s_part[0] + s_part[1]);
}

extern "C" void kernel_launch(void* const* d_in, const int* in_sizes, int n_in,
                              void* d_out, int out_size, void* d_ws, size_t ws_size,
                              hipStream_t stream) {
    const float* poseA = (const float*)d_in[0];
    const float* poseB = (const float*)d_in[1];
    const float* offA  = (const float*)d_in[2];
    const float* offB  = (const float*)d_in[3];
    const float* tA    = (const float*)d_in[4];
    const float* tB    = (const float*)d_in[5];
    float* out = (float*)d_out;

    const int F = in_sizes[0] / 144;          // 65536
    const int blocks = F / 128;               // 512 = 2 blocks/CU exactly
    const float inv_count = 1.0f / ((float)F * 15.0f);

    hipMemsetAsync(out, 0, sizeof(float), stream);
    ee_loss_kernel<<<blocks, 256, 0, stream>>>(poseA, poseB, offA, offB, tA, tB,
                                               out, inv_count);
}